// Round 12
// baseline (94.210 us; speedup 1.0000x reference)
//
#include <hip/hip_runtime.h>
#include <hip/hip_fp16.h>
#include <math.h>

#define IN_CH 32
#define K_OUT 4
#define KI (K_OUT * IN_CH)        // 128 outputs per node
#define BATCH_NODES 8             // nodes staged per wave-batch (1KB)
#define BATCH_FLOATS (BATCH_NODES * IN_CH)   // 256

typedef _Float16 h2_t __attribute__((ext_vector_type(2)));

// fp16x2 dot with fp32 accumulate: uses v_dot2_f32_f16 when available.
__device__ __forceinline__ float dot2acc(unsigned int a, unsigned int b, float c) {
#if defined(__has_builtin)
#if __has_builtin(__builtin_amdgcn_fdot2)
    return __builtin_amdgcn_fdot2(__builtin_bit_cast(h2_t, a),
                                  __builtin_bit_cast(h2_t, b), c, false);
#else
    __half2 ha = *(__half2*)&a, hb = *(__half2*)&b;
    float2 fa = __half22float2(ha), fb = __half22float2(hb);
    return fmaf(fa.y, fb.y, fmaf(fa.x, fb.x, c));
#endif
#else
    __half2 ha = *(__half2*)&a, hb = *(__half2*)&b;
    float2 fa = __half22float2(ha), fb = __half22float2(hb);
    return fmaf(fa.y, fb.y, fmaf(fa.x, fb.x, c));
#endif
}

// ---------------------------------------------------------------------------
// Prep v5 (unchanged from r11): all global access lane-varying & coalesced.
// Wave stages 8 contiguous node-rows (1KB) via registers (prefetched one
// batch ahead), converts x16 from the same registers, computes z with lane l
// owning T rows 4*(l&31)..+3 in VGPRs; LDS reads are 2-address broadcasts.
// ---------------------------------------------------------------------------
__global__ __launch_bounds__(128)
void prep_kernel(const float* __restrict__ x,
                 const float* __restrict__ T,
                 __half* __restrict__ z16,
                 __half* __restrict__ x16,
                 int n_nodes, int total_waves) {
    __shared__ float lds[2][BATCH_FLOATS];   // [wave-in-block][256 floats]
    const int wv = threadIdx.x >> 6;
    const int l  = threadIdx.x & 63;
    const int gwave = (blockIdx.x * (blockDim.x >> 6)) + wv;

    const int kbase = (l & 31) * 4;
    float tr[4][IN_CH];
#pragma unroll
    for (int r = 0; r < 4; ++r) {
        const float4* Tp = (const float4*)(T + (size_t)(kbase + r) * IN_CH);
#pragma unroll
        for (int q = 0; q < 8; ++q) {
            float4 v = Tp[q];
            tr[r][q * 4 + 0] = v.x; tr[r][q * 4 + 1] = v.y;
            tr[r][q * 4 + 2] = v.z; tr[r][q * 4 + 3] = v.w;
        }
    }

    const long long ftotal = (long long)n_nodes * IN_CH;
    const int n_batches = (n_nodes + BATCH_NODES - 1) / BATCH_NODES;

    int b = gwave;
    if (b >= n_batches) return;

    long long fidx = (long long)b * BATCH_FLOATS + l * 4;
    long long fclamp = fidx + 4 > ftotal ? ftotal - 4 : fidx;
    float4 stg = *(const float4*)(x + fclamp);
    bool st_ok = (fidx == fclamp);

    while (true) {
        ((float4*)lds[wv])[l] = stg;

        if (st_ok) {
            __half2 h0 = __floats2half2_rn(stg.x, stg.y);
            __half2 h1 = __floats2half2_rn(stg.z, stg.w);
            uint2 pk;
            pk.x = *(unsigned int*)&h0;
            pk.y = *(unsigned int*)&h1;
            *(uint2*)(x16 + fidx) = pk;
        }

        const int bn = b + total_waves;
        if (bn < n_batches) {
            fidx = (long long)bn * BATCH_FLOATS + l * 4;
            fclamp = fidx + 4 > ftotal ? ftotal - 4 : fidx;
            stg = *(const float4*)(x + fclamp);
            st_ok = (fidx == fclamp);
        }

#pragma unroll
        for (int p = 0; p < 4; ++p) {
            const int lrow = p * 2 + (l >> 5);
            const int node = b * BATCH_NODES + lrow;
            const float4* xrow = (const float4*)(lds[wv] + lrow * IN_CH);

            float a0 = 0.f, a1 = 0.f, a2 = 0.f, a3 = 0.f;
#pragma unroll
            for (int q = 0; q < 8; ++q) {
                float4 xq = xrow[q];
                a0 = fmaf(tr[0][q*4+0], xq.x, a0); a0 = fmaf(tr[0][q*4+1], xq.y, a0);
                a0 = fmaf(tr[0][q*4+2], xq.z, a0); a0 = fmaf(tr[0][q*4+3], xq.w, a0);
                a1 = fmaf(tr[1][q*4+0], xq.x, a1); a1 = fmaf(tr[1][q*4+1], xq.y, a1);
                a1 = fmaf(tr[1][q*4+2], xq.z, a1); a1 = fmaf(tr[1][q*4+3], xq.w, a1);
                a2 = fmaf(tr[2][q*4+0], xq.x, a2); a2 = fmaf(tr[2][q*4+1], xq.y, a2);
                a2 = fmaf(tr[2][q*4+2], xq.z, a2); a2 = fmaf(tr[2][q*4+3], xq.w, a2);
                a3 = fmaf(tr[3][q*4+0], xq.x, a3); a3 = fmaf(tr[3][q*4+1], xq.y, a3);
                a3 = fmaf(tr[3][q*4+2], xq.z, a3); a3 = fmaf(tr[3][q*4+3], xq.w, a3);
            }

            if (node < n_nodes) {
                __half2 ha = __floats2half2_rn(a0, a1);
                __half2 hb = __floats2half2_rn(a2, a3);
                uint2 pk;
                pk.x = *(unsigned int*)&ha;
                pk.y = *(unsigned int*)&hb;
                *(uint2*)(z16 + (size_t)node * KI + kbase) = pk;
            }
        }

        if (bn >= n_batches) break;
        b = bn;
    }
}

// ---------------------------------------------------------------------------
// Edge kernel v2: PERSISTENT grid-stride, 2048 blocks (8/CU at VGPR=16 ->
// steady ~32 waves/CU vs 67% avg for the 25000-block drain). Consecutive
// iterations are independent -> compiler pipelines ~2 iterations = ~10
// loads in flight per thread. Body identical: quad per edge, fp16 ops,
// fp32 accum, 5 compulsory lines/edge, NT idx/out streams.
// ---------------------------------------------------------------------------
__global__ __launch_bounds__(256)
void edge_kernel_quad16(const __half* __restrict__ x16,
                        const __half* __restrict__ z16,
                        const int* __restrict__ src,
                        const int* __restrict__ dst,
                        float* __restrict__ out,
                        int n_edges) {
    const int l = threadIdx.x & 3;
    const int qstride = (blockDim.x >> 2) * gridDim.x;
    int q = blockIdx.x * (blockDim.x >> 2) + (threadIdx.x >> 2);

    for (; q < n_edges; q += qstride) {
        const int s = __builtin_nontemporal_load(src + q);
        const int d = __builtin_nontemporal_load(dst + q);

        const uint4 xv = ((const uint4*)x16)[(size_t)s * 4 + l];
        const uint4* zrow = (const uint4*)z16 + (size_t)d * 16;
        const uint4 z0 = zrow[0 + l];
        const uint4 z1 = zrow[4 + l];
        const uint4 z2 = zrow[8 + l];
        const uint4 z3 = zrow[12 + l];

        float p0 = 0.f, p1 = 0.f, p2 = 0.f, p3 = 0.f;
        p0 = dot2acc(xv.x, z0.x, p0); p0 = dot2acc(xv.y, z0.y, p0);
        p0 = dot2acc(xv.z, z0.z, p0); p0 = dot2acc(xv.w, z0.w, p0);

        p1 = dot2acc(xv.x, z1.x, p1); p1 = dot2acc(xv.y, z1.y, p1);
        p1 = dot2acc(xv.z, z1.z, p1); p1 = dot2acc(xv.w, z1.w, p1);

        p2 = dot2acc(xv.x, z2.x, p2); p2 = dot2acc(xv.y, z2.y, p2);
        p2 = dot2acc(xv.z, z2.z, p2); p2 = dot2acc(xv.w, z2.w, p2);

        p3 = dot2acc(xv.x, z3.x, p3); p3 = dot2acc(xv.y, z3.y, p3);
        p3 = dot2acc(xv.z, z3.z, p3); p3 = dot2acc(xv.w, z3.w, p3);

        float send01 = (l & 1) ? p0 : p1;
        float recv01 = __shfl_xor(send01, 1);
        float a01 = ((l & 1) ? p1 : p0) + recv01;
        float send23 = (l & 1) ? p2 : p3;
        float recv23 = __shfl_xor(send23, 1);
        float a23 = ((l & 1) ? p3 : p2) + recv23;
        float send = (l & 2) ? a01 : a23;
        float recv = __shfl_xor(send, 2);
        float r = ((l & 2) ? a23 : a01) + recv;

        __builtin_nontemporal_store(tanhf(r), out + (size_t)q * 4 + l);
    }
}

// ---------------------------------------------------------------------------
// Fallback: direct quadratic form per edge (no workspace).
// ---------------------------------------------------------------------------
__global__ void edge_direct_kernel(const float* __restrict__ x,
                                   const float* __restrict__ T,
                                   const int* __restrict__ src,
                                   const int* __restrict__ dst,
                                   float* __restrict__ out,
                                   int n_edges) {
    int e = blockIdx.x * blockDim.x + threadIdx.x;
    if (e >= n_edges) return;

    const int s = src[e];
    const int d = dst[e];

    float xs[IN_CH], xd[IN_CH];
#pragma unroll
    for (int j = 0; j < IN_CH; ++j) {
        xs[j] = x[(size_t)s * IN_CH + j];
        xd[j] = x[(size_t)d * IN_CH + j];
    }

    float resv[K_OUT];
#pragma unroll
    for (int k = 0; k < K_OUT; ++k) {
        float acc = 0.f;
        for (int i = 0; i < IN_CH; ++i) {
            const float* Trow = T + ((size_t)k * IN_CH + i) * IN_CH;
            float yi = 0.f;
#pragma unroll
            for (int j = 0; j < IN_CH; ++j)
                yi = fmaf(Trow[j], xd[j], yi);
            acc = fmaf(xs[i], yi, acc);
        }
        resv[k] = tanhf(acc);
    }
    ((float4*)out)[e] = make_float4(resv[0], resv[1], resv[2], resv[3]);
}

extern "C" void kernel_launch(void* const* d_in, const int* in_sizes, int n_in,
                              void* d_out, int out_size, void* d_ws, size_t ws_size,
                              hipStream_t stream) {
    const float* x  = (const float*)d_in[0];
    const int*   ei = (const int*)d_in[1];
    const float* T  = (const float*)d_in[2];
    float* out      = (float*)d_out;

    const int n_nodes = in_sizes[0] / IN_CH;
    const int n_edges = in_sizes[1] / 2;
    const int* src = ei;
    const int* dst = ei + n_edges;

    // Workspace: z16 then x16 (both 256B-aligned)
    const size_t z16_bytes = (size_t)n_nodes * KI * sizeof(__half);
    const size_t x16_off   = (z16_bytes + 255) & ~(size_t)255;
    const size_t need      = x16_off + (size_t)n_nodes * IN_CH * sizeof(__half);

    const int threads = 256;

    if (ws_size >= need && n_nodes >= BATCH_NODES) {
        __half* z16 = (__half*)d_ws;
        __half* x16 = (__half*)((char*)d_ws + x16_off);

        // prep: 1024 blocks x 128 thr = 2048 waves, grid-stride over batches
        const int pblocks = 1024;
        const int total_waves = pblocks * 2;
        prep_kernel<<<pblocks, 128, 0, stream>>>(x, T, z16, x16, n_nodes, total_waves);

        // edge: persistent 2048 blocks (8/CU), grid-stride over quads
        edge_kernel_quad16<<<2048, threads, 0, stream>>>(
            x16, z16, src, dst, out, n_edges);
    } else {
        const int eblocks = (n_edges + threads - 1) / threads;
        edge_direct_kernel<<<eblocks, threads, 0, stream>>>(x, T, src, dst, out, n_edges);
    }
}

// Round 13
// 91.084 us; speedup vs baseline: 1.0343x; 1.0343x over previous
//
#include <hip/hip_runtime.h>
#include <hip/hip_fp16.h>
#include <math.h>

#define IN_CH 32
#define K_OUT 4
#define KI (K_OUT * IN_CH)        // 128 outputs per node
#define BATCH_NODES 8             // nodes staged per wave-batch (1KB)
#define BATCH_FLOATS (BATCH_NODES * IN_CH)   // 256

typedef _Float16 h2_t __attribute__((ext_vector_type(2)));

// fp16x2 dot with fp32 accumulate: uses v_dot2_f32_f16 when available.
__device__ __forceinline__ float dot2acc(unsigned int a, unsigned int b, float c) {
#if defined(__has_builtin)
#if __has_builtin(__builtin_amdgcn_fdot2)
    return __builtin_amdgcn_fdot2(__builtin_bit_cast(h2_t, a),
                                  __builtin_bit_cast(h2_t, b), c, false);
#else
    __half2 ha = *(__half2*)&a, hb = *(__half2*)&b;
    float2 fa = __half22float2(ha), fb = __half22float2(hb);
    return fmaf(fa.y, fb.y, fmaf(fa.x, fb.x, c));
#endif
#else
    __half2 ha = *(__half2*)&a, hb = *(__half2*)&b;
    float2 fa = __half22float2(ha), fb = __half22float2(hb);
    return fmaf(fa.y, fb.y, fmaf(fa.x, fb.x, c));
#endif
}

// ---------------------------------------------------------------------------
// Prep v5: all global access lane-varying & coalesced (r8-r10 lesson:
// wave-uniform loads scalarize to in-order SMEM and serialize).
// Wave stages 8 contiguous node-rows (1KB) via registers (prefetched one
// batch ahead), converts x16 from the same registers, computes z with lane l
// owning T rows 4*(l&31)..+3 in VGPRs; LDS reads are 2-address broadcasts.
// ---------------------------------------------------------------------------
__global__ __launch_bounds__(128)
void prep_kernel(const float* __restrict__ x,
                 const float* __restrict__ T,
                 __half* __restrict__ z16,
                 __half* __restrict__ x16,
                 int n_nodes, int total_waves) {
    __shared__ float lds[2][BATCH_FLOATS];   // [wave-in-block][256 floats]
    const int wv = threadIdx.x >> 6;
    const int l  = threadIdx.x & 63;
    const int gwave = (blockIdx.x * (blockDim.x >> 6)) + wv;

    const int kbase = (l & 31) * 4;
    float tr[4][IN_CH];
#pragma unroll
    for (int r = 0; r < 4; ++r) {
        const float4* Tp = (const float4*)(T + (size_t)(kbase + r) * IN_CH);
#pragma unroll
        for (int q = 0; q < 8; ++q) {
            float4 v = Tp[q];
            tr[r][q * 4 + 0] = v.x; tr[r][q * 4 + 1] = v.y;
            tr[r][q * 4 + 2] = v.z; tr[r][q * 4 + 3] = v.w;
        }
    }

    const long long ftotal = (long long)n_nodes * IN_CH;
    const int n_batches = (n_nodes + BATCH_NODES - 1) / BATCH_NODES;

    int b = gwave;
    if (b >= n_batches) return;

    long long fidx = (long long)b * BATCH_FLOATS + l * 4;
    long long fclamp = fidx + 4 > ftotal ? ftotal - 4 : fidx;
    float4 stg = *(const float4*)(x + fclamp);
    bool st_ok = (fidx == fclamp);

    while (true) {
        ((float4*)lds[wv])[l] = stg;

        if (st_ok) {
            __half2 h0 = __floats2half2_rn(stg.x, stg.y);
            __half2 h1 = __floats2half2_rn(stg.z, stg.w);
            uint2 pk;
            pk.x = *(unsigned int*)&h0;
            pk.y = *(unsigned int*)&h1;
            *(uint2*)(x16 + fidx) = pk;
        }

        const int bn = b + total_waves;
        if (bn < n_batches) {
            fidx = (long long)bn * BATCH_FLOATS + l * 4;
            fclamp = fidx + 4 > ftotal ? ftotal - 4 : fidx;
            stg = *(const float4*)(x + fclamp);
            st_ok = (fidx == fclamp);
        }

#pragma unroll
        for (int p = 0; p < 4; ++p) {
            const int lrow = p * 2 + (l >> 5);
            const int node = b * BATCH_NODES + lrow;
            const float4* xrow = (const float4*)(lds[wv] + lrow * IN_CH);

            float a0 = 0.f, a1 = 0.f, a2 = 0.f, a3 = 0.f;
#pragma unroll
            for (int q = 0; q < 8; ++q) {
                float4 xq = xrow[q];
                a0 = fmaf(tr[0][q*4+0], xq.x, a0); a0 = fmaf(tr[0][q*4+1], xq.y, a0);
                a0 = fmaf(tr[0][q*4+2], xq.z, a0); a0 = fmaf(tr[0][q*4+3], xq.w, a0);
                a1 = fmaf(tr[1][q*4+0], xq.x, a1); a1 = fmaf(tr[1][q*4+1], xq.y, a1);
                a1 = fmaf(tr[1][q*4+2], xq.z, a1); a1 = fmaf(tr[1][q*4+3], xq.w, a1);
                a2 = fmaf(tr[2][q*4+0], xq.x, a2); a2 = fmaf(tr[2][q*4+1], xq.y, a2);
                a2 = fmaf(tr[2][q*4+2], xq.z, a2); a2 = fmaf(tr[2][q*4+3], xq.w, a2);
                a3 = fmaf(tr[3][q*4+0], xq.x, a3); a3 = fmaf(tr[3][q*4+1], xq.y, a3);
                a3 = fmaf(tr[3][q*4+2], xq.z, a3); a3 = fmaf(tr[3][q*4+3], xq.w, a3);
            }

            if (node < n_nodes) {
                __half2 ha = __floats2half2_rn(a0, a1);
                __half2 hb = __floats2half2_rn(a2, a3);
                uint2 pk;
                pk.x = *(unsigned int*)&ha;
                pk.y = *(unsigned int*)&hb;
                *(uint2*)(z16 + (size_t)node * KI + kbase) = pk;
            }
        }

        if (bn >= n_batches) break;
        b = bn;
    }
}

// ---------------------------------------------------------------------------
// Edge kernel (r11 optimum, reverted from r12's persistent variant which
// regressed 66->71us): one quad per edge, bounded launch. Quad per edge,
// fp16 operands, fp32 accumulate. 5 compulsory lines/edge random-gather at
// the measured ~3.85 TB/s random-line fill ceiling (r12 falsified the
// latency-bound hypothesis: more waves/ILP did not help). NT hints keep the
// idx/out streams from polluting L2.
// ---------------------------------------------------------------------------
__global__ __launch_bounds__(256)
void edge_kernel_quad16(const __half* __restrict__ x16,
                        const __half* __restrict__ z16,
                        const int* __restrict__ src,
                        const int* __restrict__ dst,
                        float* __restrict__ out,
                        int n_edges) {
    const int t = blockIdx.x * blockDim.x + threadIdx.x;
    const int e = t >> 2;
    const int l = t & 3;
    if (e >= n_edges) return;

    const int s = __builtin_nontemporal_load(src + e);
    const int d = __builtin_nontemporal_load(dst + e);

    const uint4 xv = ((const uint4*)x16)[(size_t)s * 4 + l];
    const uint4* zrow = (const uint4*)z16 + (size_t)d * 16;
    const uint4 z0 = zrow[0 + l];
    const uint4 z1 = zrow[4 + l];
    const uint4 z2 = zrow[8 + l];
    const uint4 z3 = zrow[12 + l];

    float p0 = 0.f, p1 = 0.f, p2 = 0.f, p3 = 0.f;
    p0 = dot2acc(xv.x, z0.x, p0); p0 = dot2acc(xv.y, z0.y, p0);
    p0 = dot2acc(xv.z, z0.z, p0); p0 = dot2acc(xv.w, z0.w, p0);

    p1 = dot2acc(xv.x, z1.x, p1); p1 = dot2acc(xv.y, z1.y, p1);
    p1 = dot2acc(xv.z, z1.z, p1); p1 = dot2acc(xv.w, z1.w, p1);

    p2 = dot2acc(xv.x, z2.x, p2); p2 = dot2acc(xv.y, z2.y, p2);
    p2 = dot2acc(xv.z, z2.z, p2); p2 = dot2acc(xv.w, z2.w, p2);

    p3 = dot2acc(xv.x, z3.x, p3); p3 = dot2acc(xv.y, z3.y, p3);
    p3 = dot2acc(xv.z, z3.z, p3); p3 = dot2acc(xv.w, z3.w, p3);

    float send01 = (l & 1) ? p0 : p1;
    float recv01 = __shfl_xor(send01, 1);
    float a01 = ((l & 1) ? p1 : p0) + recv01;
    float send23 = (l & 1) ? p2 : p3;
    float recv23 = __shfl_xor(send23, 1);
    float a23 = ((l & 1) ? p3 : p2) + recv23;
    float send = (l & 2) ? a01 : a23;
    float recv = __shfl_xor(send, 2);
    float r = ((l & 2) ? a23 : a01) + recv;

    __builtin_nontemporal_store(tanhf(r), out + t);
}

// ---------------------------------------------------------------------------
// Fallback: direct quadratic form per edge (no workspace).
// ---------------------------------------------------------------------------
__global__ void edge_direct_kernel(const float* __restrict__ x,
                                   const float* __restrict__ T,
                                   const int* __restrict__ src,
                                   const int* __restrict__ dst,
                                   float* __restrict__ out,
                                   int n_edges) {
    int e = blockIdx.x * blockDim.x + threadIdx.x;
    if (e >= n_edges) return;

    const int s = src[e];
    const int d = dst[e];

    float xs[IN_CH], xd[IN_CH];
#pragma unroll
    for (int j = 0; j < IN_CH; ++j) {
        xs[j] = x[(size_t)s * IN_CH + j];
        xd[j] = x[(size_t)d * IN_CH + j];
    }

    float resv[K_OUT];
#pragma unroll
    for (int k = 0; k < K_OUT; ++k) {
        float acc = 0.f;
        for (int i = 0; i < IN_CH; ++i) {
            const float* Trow = T + ((size_t)k * IN_CH + i) * IN_CH;
            float yi = 0.f;
#pragma unroll
            for (int j = 0; j < IN_CH; ++j)
                yi = fmaf(Trow[j], xd[j], yi);
            acc = fmaf(xs[i], yi, acc);
        }
        resv[k] = tanhf(acc);
    }
    ((float4*)out)[e] = make_float4(resv[0], resv[1], resv[2], resv[3]);
}

extern "C" void kernel_launch(void* const* d_in, const int* in_sizes, int n_in,
                              void* d_out, int out_size, void* d_ws, size_t ws_size,
                              hipStream_t stream) {
    const float* x  = (const float*)d_in[0];
    const int*   ei = (const int*)d_in[1];
    const float* T  = (const float*)d_in[2];
    float* out      = (float*)d_out;

    const int n_nodes = in_sizes[0] / IN_CH;
    const int n_edges = in_sizes[1] / 2;
    const int* src = ei;
    const int* dst = ei + n_edges;

    // Workspace: z16 then x16 (both 256B-aligned)
    const size_t z16_bytes = (size_t)n_nodes * KI * sizeof(__half);
    const size_t x16_off   = (z16_bytes + 255) & ~(size_t)255;
    const size_t need      = x16_off + (size_t)n_nodes * IN_CH * sizeof(__half);

    const int threads = 256;

    if (ws_size >= need && n_nodes >= BATCH_NODES) {
        __half* z16 = (__half*)d_ws;
        __half* x16 = (__half*)((char*)d_ws + x16_off);

        // prep: 1024 blocks x 128 thr = 2048 waves, grid-stride over batches
        const int pblocks = 1024;
        const int total_waves = pblocks * 2;
        prep_kernel<<<pblocks, 128, 0, stream>>>(x, T, z16, x16, n_nodes, total_waves);

        // edge: one quad (4 lanes) per edge, bounded launch (r11 optimum)
        const long long total = (long long)n_edges * 4;
        const int blocks = (int)((total + threads - 1) / threads);
        edge_kernel_quad16<<<blocks, threads, 0, stream>>>(
            x16, z16, src, dst, out, n_edges);
    } else {
        const int eblocks = (n_edges + threads - 1) / threads;
        edge_direct_kernel<<<eblocks, threads, 0, stream>>>(x, T, src, dst, out, n_edges);
    }
}